// Round 7
// baseline (2109.566 us; speedup 1.0000x reference)
//
#include <hip/hip_runtime.h>
#include <stdint.h>

typedef __attribute__((ext_vector_type(8))) short short8;
typedef __attribute__((ext_vector_type(4))) float f32x4;

__device__ __forceinline__ unsigned short f2bf(float f) {
  union { float f; uint32_t u; } v; v.f = f;
  uint32_t u = v.u;
  u += 0x7FFF + ((u >> 16) & 1);   // round-to-nearest-even
  return (unsigned short)(u >> 16);
}
__device__ __forceinline__ float bf2f(unsigned short h) {
  union { uint32_t u; float f; } v; v.u = ((uint32_t)h) << 16;
  return v.f;
}

// ---------------- convert fp32 -> bf16 (8 elems/thread) -------------------
__global__ void conv_kernel(const float* __restrict__ in,
                            unsigned short* __restrict__ out, int n) {
  long i = ((long)blockIdx.x * blockDim.x + threadIdx.x) * 8;
  if (i >= n) return;
  float4 a = *(const float4*)(in + i);
  float4 b = *(const float4*)(in + i + 4);
  short8 s;
  s[0] = (short)f2bf(a.x); s[1] = (short)f2bf(a.y);
  s[2] = (short)f2bf(a.z); s[3] = (short)f2bf(a.w);
  s[4] = (short)f2bf(b.x); s[5] = (short)f2bf(b.y);
  s[6] = (short)f2bf(b.z); s[7] = (short)f2bf(b.w);
  *(short8*)(out + i) = s;
}

// concat-convert: src [R][1024] fp32 -> dst[row][colbase + col] bf16, ldo=2048
__global__ void convcat_kernel(const float* __restrict__ in,
                               unsigned short* __restrict__ out,
                               int colbase, int n) {
  long i = ((long)blockIdx.x * blockDim.x + threadIdx.x) * 8;
  if (i >= n) return;
  float4 a = *(const float4*)(in + i);
  float4 b = *(const float4*)(in + i + 4);
  short8 s;
  s[0] = (short)f2bf(a.x); s[1] = (short)f2bf(a.y);
  s[2] = (short)f2bf(a.z); s[3] = (short)f2bf(a.w);
  s[4] = (short)f2bf(b.x); s[5] = (short)f2bf(b.y);
  s[6] = (short)f2bf(b.z); s[7] = (short)f2bf(b.w);
  long row = i >> 10, col = i & 1023;
  *(short8*)(out + row * 2048 + colbase + col) = s;
}

// convert with per-column scale fold: out[i] = bf16(in[i] * scale[i & 2047])
__global__ void convs_kernel(const float* __restrict__ in,
                             const float* __restrict__ scale,
                             unsigned short* __restrict__ out, int n) {
  long i = ((long)blockIdx.x * blockDim.x + threadIdx.x) * 8;
  if (i >= n) return;
  short8 s;
#pragma unroll
  for (int j = 0; j < 8; ++j)
    s[j] = (short)f2bf(in[i + j] * scale[(i + j) & 2047]);
  *(short8*)(out + i) = s;
}

// transpose-convert: out[C][R] = bf16(in[R][C]^T). block (32,8), grid (C/32, R/32)
__global__ void tconv_kernel(const float* __restrict__ in, int R, int C,
                             unsigned short* __restrict__ out) {
  __shared__ float tile[32][33];
  int c0 = blockIdx.x * 32, r0 = blockIdx.y * 32;
  int tx = threadIdx.x, ty = threadIdx.y;
#pragma unroll
  for (int i = 0; i < 32; i += 8)
    tile[ty + i][tx] = in[(long)(r0 + ty + i) * C + c0 + tx];
  __syncthreads();
#pragma unroll
  for (int i = 0; i < 32; i += 8)
    out[(long)(c0 + ty + i) * R + r0 + tx] = f2bf(tile[tx][ty + i]);
}

// ---------------- 256x256 bf16 GEMM, 8-phase + register prefetch-1 --------
// C = A @ W^T (+ epilogue). BK=64, 8 waves (2M x 4N), interleaved frag map.
// Phase q issues ds_reads for phase q+1's fragments (alt register set), then
// MFMAs on registers loaded in phase q-1 -> LDS pipe overlaps MFMA pipe.
// Stage lead 6 phases; watermarks VMW(8/-/10/10/8/-/10/10); 1 barrier/phase.
enum { EPI_BIAS = 0, EPI_GATE = 2, EPI_LNF32 = 4 };

#define VMW(N) asm volatile("s_waitcnt vmcnt(" #N ")" ::: "memory")
#define SBAR() __builtin_amdgcn_s_barrier()
#define SCB() __builtin_amdgcn_sched_barrier(0)

#define STG(D, OP, HALF, PTR, LD8)                                            \
  { char* lp_ = (char*)smem + ((D)*65536 + (OP)*32768 + (HALF)*16384 + w*2048); \
    __builtin_amdgcn_global_load_lds(                                         \
        (const __attribute__((address_space(1))) void*)(PTR),                 \
        (__attribute__((address_space(3))) void*)lp_, 16, 0, 0);              \
    __builtin_amdgcn_global_load_lds(                                         \
        (const __attribute__((address_space(1))) void*)((PTR) + (LD8)),       \
        (__attribute__((address_space(3))) void*)(lp_ + 1024), 16, 0, 0);     \
    (PTR) += 64; }

#define RDA(D, KK) ((KK) ? ((D) ? pA11 : pA01) : ((D) ? pA10 : pA00))
#define RDB(D, KK) ((KK) ? ((D) ? pB11 : pB01) : ((D) ? pB10 : pB00))

// issue next-phase fragment reads (consumed one phase later)
#define RD_A(SET, D, H)                                                       \
  _Pragma("unroll") for (int mi = 0; mi < 4; ++mi) {                          \
    SET[mi][0] = *(const short8*)(RDA(D, 0) + (H)*16384 + mi * 4096);         \
    SET[mi][1] = *(const short8*)(RDA(D, 1) + (H)*16384 + mi * 4096);         \
  }
#define RD_B(SET, D, H)                                                       \
  _Pragma("unroll") for (int ni = 0; ni < 2; ++ni) {                          \
    SET[ni][0] = *(const short8*)(RDB(D, 0) + (H)*16384 + ni * 8192);         \
    SET[ni][1] = *(const short8*)(RDB(D, 1) + (H)*16384 + ni * 8192);         \
  }

// MFMA cluster on registers loaded last phase
#define MM(MQ, NQ, ASET, BSET)                                                \
  SCB();                                                                      \
  __builtin_amdgcn_s_setprio(1);                                              \
  _Pragma("unroll") for (int mi = 0; mi < 4; ++mi)                            \
  _Pragma("unroll") for (int ni = 0; ni < 2; ++ni) {                          \
    acc[(MQ)*4+mi][(NQ)*2+ni] = __builtin_amdgcn_mfma_f32_16x16x32_bf16(      \
        ASET[mi][0], BSET[ni][0], acc[(MQ)*4+mi][(NQ)*2+ni], 0, 0, 0);        \
    acc[(MQ)*4+mi][(NQ)*2+ni] = __builtin_amdgcn_mfma_f32_16x16x32_bf16(      \
        ASET[mi][1], BSET[ni][1], acc[(MQ)*4+mi][(NQ)*2+ni], 0, 0, 0);        \
  }                                                                           \
  __builtin_amdgcn_s_setprio(0);                                              \
  SCB()

template <int EPI, int SWZ>
__global__ __launch_bounds__(512, 2)
void gemm8p_kernel(const unsigned short* __restrict__ A, int lda,
                   const unsigned short* __restrict__ W, int ldw,
                   int K, int ldc, int nmt,
                   int pairBase, long aoff, long woff, long coff,
                   const float* __restrict__ bias,
                   const float* __restrict__ bias2,
                   const unsigned short* __restrict__ Xg,
                   const unsigned short* __restrict__ Xc, int ldx,
                   const float2* __restrict__ stats,
                   void* __restrict__ Cv) {
  __shared__ unsigned short smem[65536];  // 128 KB

  const int tid = threadIdx.x, lane = tid & 63, w = tid >> 6;
  const int wm = w >> 2, wn = w & 3;

  int bid = blockIdx.x;
  if (bid >= pairBase) {
    bid -= pairBase;
    A += aoff; W += woff;
    Cv = (void*)((unsigned short*)Cv + coff);
  }
  int mt, nt;
  if (SWZ) {  // 512 blocks: XCD x owns mt [x*8, x*8+8), sweeps 8 nt
    const int xcd = bid & 7, seq = bid >> 3;
    nt = seq >> 3;
    mt = xcd * 8 + (seq & 7);
  } else {
    mt = bid % nmt;
    nt = bid / nmt;
  }
  const long tileM = (long)mt * 256, tileN = (long)nt * 256;

  // ---- staging stream pointers (monotone, +64 elems per stage event) -----
  const int sRow = w * 16 + (lane >> 3);
  const int sCol = (((lane & 7) ^ ((lane >> 3) & 7)) * 8);
  const unsigned short* pSA0 = A + (tileM + sRow) * (long)lda + sCol;
  const unsigned short* pSA1 = pSA0 + 128 * (long)lda;
  const unsigned short* pSB0 = W + (tileN + sRow) * (long)ldw + sCol;
  const unsigned short* pSB1 = pSB0 + 128 * (long)ldw;
  const long lda8 = 8 * (long)lda, ldw8 = 8 * (long)ldw;

  // ---- LDS read base pointers (per d-buffer x kk), const offsets after ---
  const int fr = lane & 15, kc = lane >> 4, l7 = lane & 7;
  const char* pA00 = (const char*)smem + (wm * 16 + fr) * 128 + ((kc) ^ l7) * 16;
  const char* pA01 = (const char*)smem + (wm * 16 + fr) * 128 + ((4 + kc) ^ l7) * 16;
  const char* pA10 = pA00 + 65536;
  const char* pA11 = pA01 + 65536;
  const char* pB00 = (const char*)smem + 32768 + (wn * 16 + fr) * 128 + ((kc) ^ l7) * 16;
  const char* pB01 = (const char*)smem + 32768 + (wn * 16 + fr) * 128 + ((4 + kc) ^ l7) * 16;
  const char* pB10 = pB00 + 65536;
  const char* pB11 = pB01 + 65536;

  f32x4 acc[8][4] = {};
  short8 aHX[4][2], aHY[4][2];   // A fragment double-buffer (prefetch-1)
  short8 bq0[2][2], bq1[2][2];   // B fragment sets (by NQ)

  // ---- prologue: stage both K-tiles (FIFO = steady-state order) ----------
  STG(0, 0, 0, pSA0, lda8);  // d0.A0 kt0
  STG(0, 1, 0, pSB0, ldw8);  // d0.B0 kt0
  STG(0, 1, 1, pSB1, ldw8);  // d0.B1 kt0
  STG(0, 0, 1, pSA1, lda8);  // d0.A1 kt0
  STG(1, 0, 0, pSA0, lda8);  // d1.A0 kt1
  STG(1, 1, 0, pSB0, ldw8);  // d1.B0 kt1
  STG(1, 1, 1, pSB1, ldw8);  // d1.B1 kt1
  STG(1, 0, 1, pSA1, lda8);  // d1.A1 kt1
  VMW(12);  // d0.A0, d0.B0 arrived
  SBAR();
  RD_A(aHX, 0, 0);  // fragments for P0
  RD_B(bq0, 0, 0);

  const int NIT = K / 128;  // 2 K-tiles (BK=64) per iteration
  for (int it = 0; it < NIT - 1; ++it) {
    // P0
    RD_B(bq1, 0, 1);
    MM(0, 0, aHX, bq0); VMW(8); SBAR();
    // P1
    RD_A(aHY, 0, 1);
    STG(0, 0, 0, pSA0, lda8); STG(0, 1, 0, pSB0, ldw8);
    MM(0, 1, aHX, bq1); SBAR();
    // P2
    STG(0, 1, 1, pSB1, ldw8);
    MM(1, 0, aHY, bq0); VMW(10); SBAR();
    // P3
    RD_A(aHX, 1, 0); RD_B(bq0, 1, 0);
    STG(0, 0, 1, pSA1, lda8);
    MM(1, 1, aHY, bq1); VMW(10); SBAR();
    // P4
    RD_B(bq1, 1, 1);
    MM(0, 0, aHX, bq0); VMW(8); SBAR();
    // P5
    RD_A(aHY, 1, 1);
    STG(1, 0, 0, pSA0, lda8); STG(1, 1, 0, pSB0, ldw8);
    MM(0, 1, aHX, bq1); SBAR();
    // P6
    STG(1, 1, 1, pSB1, ldw8);
    MM(1, 0, aHY, bq0); VMW(10); SBAR();
    // P7
    RD_A(aHX, 0, 0); RD_B(bq0, 0, 0);
    STG(1, 0, 1, pSA1, lda8);
    MM(1, 1, aHY, bq1); VMW(10); SBAR();
  }
  {  // peeled drain iteration (no stages)
    RD_B(bq1, 0, 1);
    MM(0, 0, aHX, bq0); VMW(8); SBAR();
    RD_A(aHY, 0, 1);
    MM(0, 1, aHX, bq1); SBAR();
    MM(1, 0, aHY, bq0); VMW(4); SBAR();
    RD_A(aHX, 1, 0); RD_B(bq0, 1, 0);
    MM(1, 1, aHY, bq1); VMW(2); SBAR();
    RD_B(bq1, 1, 1);
    MM(0, 0, aHX, bq0); VMW(0); SBAR();
    RD_A(aHY, 1, 1);
    MM(0, 1, aHX, bq1); SBAR();
    MM(1, 0, aHY, bq0); SBAR();
    MM(1, 1, aHY, bq1);
  }

  // ---- epilogue: C/D layout col = lane&15, row = (lane>>4)*4 + reg --------
  const int cr = (lane >> 4) * 4;
  const int cc = lane & 15;
#pragma unroll
  for (int m = 0; m < 8; ++m) {
    long rr = tileM + (m >> 2) * 128 + (m & 3) * 32 + wm * 16 + cr;
#pragma unroll
    for (int n = 0; n < 4; ++n) {
      long c = tileN + (n >> 1) * 128 + (n & 1) * 64 + wn * 16 + cc;
      float b1 = bias ? bias[c] : 0.0f;
      float b2 = bias2 ? bias2[c] : 0.0f;
#pragma unroll
      for (int r = 0; r < 4; ++r) {
        long row = rr + r;
        long idx = row * (long)ldc + c;
        float v = acc[m][n][r];
        if constexpr (EPI == EPI_BIAS) {
          ((unsigned short*)Cv)[idx] = f2bf(v + b1 + b2);
        }
        if constexpr (EPI == EPI_GATE) {
          float gt = 1.0f / (1.0f + expf(-(v + b1)));
          long xix = row * (long)ldx + c;
          float gv = bf2f(Xg[xix]);   // g
          float cvv = bf2f(Xc[xix]);  // cross
          ((unsigned short*)Cv)[idx] = f2bf(gt * gv + (1.0f - gt) * cvv + gv);
        }
        if constexpr (EPI == EPI_LNF32) {
          float2 st = stats[row];  // (mu, rstd)
          ((float*)Cv)[idx] = v * st.y - st.y * st.x * b1 + b2;
        }
      }
    }
  }
}

// ---------------- per-row LN stats over 2048 cols -------------------------
__global__ __launch_bounds__(256) void lnstats_kernel(
    const unsigned short* __restrict__ in, float2* __restrict__ stats) {
  const int row = blockIdx.x;
  const int t = threadIdx.x, lane = t & 63, wave = t >> 6;
  short8 v8 = *(const short8*)&in[(long)row * 2048 + t * 8];
  float s = 0.f, s2 = 0.f;
#pragma unroll
  for (int j = 0; j < 8; ++j) {
    float x = bf2f((unsigned short)v8[j]);
    s += x; s2 += x * x;
  }
#pragma unroll
  for (int off = 1; off < 64; off <<= 1) {
    s  += __shfl_xor(s, off);
    s2 += __shfl_xor(s2, off);
  }
  __shared__ float red[8];
  if (lane == 0) { red[wave] = s; red[4 + wave] = s2; }
  __syncthreads();
  if (t == 0) {
    float ts  = red[0] + red[1] + red[2] + red[3];
    float ts2 = red[4] + red[5] + red[6] + red[7];
    float mean = ts * (1.0f / 2048.0f);
    float var  = ts2 * (1.0f / 2048.0f) - mean * mean;
    stats[row] = make_float2(mean, rsqrtf(var + 1e-5f));
  }
}

// bcV[c] = o1b+o2b + wO1b[c]·bv1 + wO2b[c]·bv2 + Wc1[c]·tp_b + Wc2[c]·gp_b
__global__ void biascomp_kernel(const unsigned short* __restrict__ wO1b,
                                const unsigned short* __restrict__ wO2b,
                                const unsigned short* __restrict__ Wc1,
                                const unsigned short* __restrict__ Wc2,
                                const float* __restrict__ bv1,
                                const float* __restrict__ bv2,
                                const float* __restrict__ tpb,
                                const float* __restrict__ gpb,
                                const float* __restrict__ o1b,
                                const float* __restrict__ o2b,
                                float* __restrict__ bcV) {
  int c = blockIdx.x * 256 + threadIdx.x;
  float s = o1b[c] + o2b[c];
  const unsigned short* r1 = wO1b + (long)c * 2048;
  const unsigned short* r2 = wO2b + (long)c * 2048;
  const unsigned short* r3 = Wc1 + (long)c * 2048;
  const unsigned short* r4 = Wc2 + (long)c * 2048;
  for (int k = 0; k < 2048; k += 8) {
    short8 a1 = *(const short8*)(r1 + k);
    short8 a2 = *(const short8*)(r2 + k);
    short8 a3 = *(const short8*)(r3 + k);
    short8 a4 = *(const short8*)(r4 + k);
#pragma unroll
    for (int j = 0; j < 8; ++j)
      s += bf2f((unsigned short)a1[j]) * bv1[k + j]
         + bf2f((unsigned short)a2[j]) * bv2[k + j]
         + bf2f((unsigned short)a3[j]) * tpb[k + j]
         + bf2f((unsigned short)a4[j]) * gpb[k + j];
  }
  bcV[c] = s;
}

// u[n] = rowsum(gamma-folded wLIN);  v[n] = dot(ln_beta, lin_w[n,:]) + lin_b[n]
__global__ void uv_kernel(const unsigned short* __restrict__ wlinp,
                          const float* __restrict__ lin_w,
                          const float* __restrict__ ln_beta,
                          const float* __restrict__ lin_b,
                          float* __restrict__ uV, float* __restrict__ vV) {
  int n = blockIdx.x * 256 + threadIdx.x;
  float u = 0.f, v = 0.f;
  const unsigned short* r1 = wlinp + (long)n * 2048;
  const float* r2 = lin_w + (long)n * 2048;
  for (int k = 0; k < 2048; k += 8) {
    short8 a1 = *(const short8*)(r1 + k);
    float4 f0 = *(const float4*)(r2 + k);
    float4 f1 = *(const float4*)(r2 + k + 4);
    float4 b0 = *(const float4*)(ln_beta + k);
    float4 b1 = *(const float4*)(ln_beta + k + 4);
#pragma unroll
    for (int j = 0; j < 8; ++j) u += bf2f((unsigned short)a1[j]);
    v += b0.x * f0.x + b0.y * f0.y + b0.z * f0.z + b0.w * f0.w
       + b1.x * f1.x + b1.y * f1.y + b1.z * f1.z + b1.w * f1.w;
  }
  uV[n] = u;
  vV[n] = v + lin_b[n];
}

// --------------------------------------------------------------------------
extern "C" void kernel_launch(void* const* d_in, const int* in_sizes, int n_in,
                              void* d_out, int out_size, void* d_ws, size_t ws_size,
                              hipStream_t stream) {
  const float* graph    = (const float*)d_in[0];
  const float* temporal = (const float*)d_in[1];
  const float* gp_w  = (const float*)d_in[2];
  const float* gp_b  = (const float*)d_in[3];
  const float* tp_w  = (const float*)d_in[4];
  const float* tp_b  = (const float*)d_in[5];
  const float* in1_w = (const float*)d_in[6];
  const float* in1_b = (const float*)d_in[7];
  const float* out1_w = (const float*)d_in[8];
  const float* out1_b = (const float*)d_in[9];
  const float* in2_w = (const float*)d_in[10];
  const float* in2_b = (const float*)d_in[11];
  const float* out2_w = (const float*)d_in[12];
  const float* out2_b = (const float*)d_in[13];
  const float* gate_w = (const float*)d_in[14];
  const float* gate_b = (const float*)d_in[15];
  const float* ln_g  = (const float*)d_in[16];
  const float* ln_b  = (const float*)d_in[17];
  const float* lin_w = (const float*)d_in[18];
  const float* lin_b = (const float*)d_in[19];

  const int Bm = 16384, F = 2048, GD = 1024;
  const long BF = (long)Bm * F, FF = (long)F * F, FG = (long)F * GD;

  // ---- ws layout (~210 MB) ----
  unsigned short* GX   = (unsigned short*)d_ws;   // [16384][4096] = [g|cross]
  unsigned short* TG   = GX + (long)Bm * 4096;    // [16384][2048] = [t|g]; later preLN
  unsigned short* PL   = TG;                      // preLN overwrites TG (dead)
  unsigned short* wLIN = TG + BF;                 // gamma-folded lin_w
  float* bcV    = (float*)(wLIN + FF);
  float* uV     = bcV + F;
  float* vV     = uV + F;
  float2* stats = (float2*)(vV + F);              // 16384 float2

  // ---- d_out scratch (88 MB, all dead before final GEMM writes d_out) ----
  unsigned short* DO    = (unsigned short*)d_out;
  unsigned short* wv1T  = DO;           // [2048][2048]
  unsigned short* wv2T  = wv1T + FF;
  unsigned short* tpT   = wv2T + FF;    // [1024][2048]
  unsigned short* gpT   = tpT + FG;
  unsigned short* Wc1   = gpT + FG;     // [2048][2048]
  unsigned short* Wc2   = Wc1 + FF;
  unsigned short* wO1b  = Wc2 + FF;
  unsigned short* wO2b  = wO1b + FF;
  unsigned short* wGATE = wO2b + FF;    // [2048][4096]
  unsigned short* wGP   = wGATE + 2 * FF;  // [2048][1024]
  unsigned short* Wcross = wGP + FG;    // [2048][2048] = [WT1|WG2]

  auto conv = [&](const float* src, unsigned short* dst, long n) {
    conv_kernel<<<dim3((unsigned)(n / 8 / 256)), 256, 0, stream>>>(src, dst, (int)n);
  };
  // inputs -> TG = [temporal | graph]
  convcat_kernel<<<dim3((unsigned)(Bm * GD / 8 / 256)), 256, 0, stream>>>(
      temporal, TG, 0, Bm * GD);
  convcat_kernel<<<dim3((unsigned)(Bm * GD / 8 / 256)), 256, 0, stream>>>(
      graph, TG, GD, Bm * GD);
  conv(gp_w, wGP, FG);
  conv(out1_w, wO1b, FF);
  conv(out2_w, wO2b, FF);
  conv(gate_w, wGATE, 2 * FF);
  convs_kernel<<<dim3((unsigned)(FF / 8 / 256)), 256, 0, stream>>>(lin_w, ln_g, wLIN, (int)FF);
  tconv_kernel<<<dim3(F / 32, F / 32), dim3(32, 8), 0, stream>>>(in1_w + 2 * FF, F, F, wv1T);
  tconv_kernel<<<dim3(F / 32, F / 32), dim3(32, 8), 0, stream>>>(in2_w + 2 * FF, F, F, wv2T);
  tconv_kernel<<<dim3(GD / 32, F / 32), dim3(32, 8), 0, stream>>>(tp_w, F, GD, tpT);
  tconv_kernel<<<dim3(GD / 32, F / 32), dim3(32, 8), 0, stream>>>(gp_w, F, GD, gpT);

  dim3 blk(512);

  // compose1 (pair): Wc1 = wO1@wv1, Wc2 = wO2@wv2   K=2048, N=2048
  gemm8p_kernel<EPI_BIAS, 0><<<dim3(128), blk, 0, stream>>>(
      wO1b, F, wv1T, F, F, F, 8,
      64, wO2b - wO1b, wv2T - wv1T, Wc2 - Wc1,
      nullptr, nullptr, nullptr, nullptr, 0, nullptr, Wc1);
  // compose2 (pair): Wcross = [Wc1@tp_w | Wc2@gp_w]  K=2048, N=1024, coff=1024
  gemm8p_kernel<EPI_BIAS, 0><<<dim3(64), blk, 0, stream>>>(
      Wc1, F, tpT, F, F, F, 8,
      32, Wc2 - Wc1, gpT - tpT, 1024,
      nullptr, nullptr, nullptr, nullptr, 0, nullptr, Wcross);
  biascomp_kernel<<<dim3(8), dim3(256), 0, stream>>>(
      wO1b, wO2b, Wc1, Wc2, in1_b + 2 * F, in2_b + 2 * F, tp_b, gp_b,
      out1_b, out2_b, bcV);
  uv_kernel<<<dim3(8), dim3(256), 0, stream>>>(wLIN, lin_w, ln_b, lin_b, uV, vV);

  // K1: g = graph @ gp_w^T + gp_b   (K=1024) -> GX cols 0..2047 (ldc=4096)
  gemm8p_kernel<EPI_BIAS, 1><<<dim3(512), blk, 0, stream>>>(
      TG + GD, F, wGP, GD, GD, 2 * F, 0, 1 << 30, 0, 0, 0,
      gp_b, nullptr, nullptr, nullptr, 0, nullptr, GX);
  // cross = TG @ Wcross^T + bcV     (K=2048) -> GX cols 2048..4095
  gemm8p_kernel<EPI_BIAS, 1><<<dim3(512), blk, 0, stream>>>(
      TG, F, Wcross, F, F, 2 * F, 0, 1 << 30, 0, 0, 0,
      bcV, nullptr, nullptr, nullptr, 0, nullptr, GX + F);
  // gate+fuse: preLN = gatefuse(GX @ wGATE^T + gate_b)  (K=4096) -> PL (=TG)
  gemm8p_kernel<EPI_GATE, 1><<<dim3(512), blk, 0, stream>>>(
      GX, 2 * F, wGATE, 2 * F, 2 * F, F, 0, 1 << 30, 0, 0, 0,
      gate_b, nullptr, GX, GX + F, 2 * F, nullptr, PL);
  // per-row LN stats
  lnstats_kernel<<<dim3(Bm), dim3(256), 0, stream>>>(PL, stats);
  // out = rstd*(preLN @ wLIN^T) - rstd*mu*u + v   (K=2048, fp32) -> d_out
  gemm8p_kernel<EPI_LNF32, 1><<<dim3(512), blk, 0, stream>>>(
      PL, F, wLIN, F, F, F, 0, 1 << 30, 0, 0, 0,
      uV, vV, nullptr, nullptr, 0, stats, (void*)d_out);
}

// Round 8
// 892.406 us; speedup vs baseline: 2.3639x; 2.3639x over previous
//
#include <hip/hip_runtime.h>
#include <stdint.h>

typedef __attribute__((ext_vector_type(8))) short short8;
typedef __attribute__((ext_vector_type(4))) float f32x4;

__device__ __forceinline__ unsigned short f2bf(float f) {
  union { float f; uint32_t u; } v; v.f = f;
  uint32_t u = v.u;
  u += 0x7FFF + ((u >> 16) & 1);   // round-to-nearest-even
  return (unsigned short)(u >> 16);
}
__device__ __forceinline__ float bf2f(unsigned short h) {
  union { uint32_t u; float f; } v; v.u = ((uint32_t)h) << 16;
  return v.f;
}

// ---------------- convert fp32 -> bf16 (8 elems/thread) -------------------
__global__ void conv_kernel(const float* __restrict__ in,
                            unsigned short* __restrict__ out, int n) {
  long i = ((long)blockIdx.x * blockDim.x + threadIdx.x) * 8;
  if (i >= n) return;
  float4 a = *(const float4*)(in + i);
  float4 b = *(const float4*)(in + i + 4);
  short8 s;
  s[0] = (short)f2bf(a.x); s[1] = (short)f2bf(a.y);
  s[2] = (short)f2bf(a.z); s[3] = (short)f2bf(a.w);
  s[4] = (short)f2bf(b.x); s[5] = (short)f2bf(b.y);
  s[6] = (short)f2bf(b.z); s[7] = (short)f2bf(b.w);
  *(short8*)(out + i) = s;
}

// concat-convert: src [R][1024] fp32 -> dst[row][colbase + col] bf16, ldo=2048
__global__ void convcat_kernel(const float* __restrict__ in,
                               unsigned short* __restrict__ out,
                               int colbase, int n) {
  long i = ((long)blockIdx.x * blockDim.x + threadIdx.x) * 8;
  if (i >= n) return;
  float4 a = *(const float4*)(in + i);
  float4 b = *(const float4*)(in + i + 4);
  short8 s;
  s[0] = (short)f2bf(a.x); s[1] = (short)f2bf(a.y);
  s[2] = (short)f2bf(a.z); s[3] = (short)f2bf(a.w);
  s[4] = (short)f2bf(b.x); s[5] = (short)f2bf(b.y);
  s[6] = (short)f2bf(b.z); s[7] = (short)f2bf(b.w);
  long row = i >> 10, col = i & 1023;
  *(short8*)(out + row * 2048 + colbase + col) = s;
}

// convert with per-column scale fold: out[i] = bf16(in[i] * scale[i & 2047])
__global__ void convs_kernel(const float* __restrict__ in,
                             const float* __restrict__ scale,
                             unsigned short* __restrict__ out, int n) {
  long i = ((long)blockIdx.x * blockDim.x + threadIdx.x) * 8;
  if (i >= n) return;
  short8 s;
#pragma unroll
  for (int j = 0; j < 8; ++j)
    s[j] = (short)f2bf(in[i + j] * scale[(i + j) & 2047]);
  *(short8*)(out + i) = s;
}

// transpose-convert: out[C][R] = bf16(in[R][C]^T). block (32,8), grid (C/32, R/32)
__global__ void tconv_kernel(const float* __restrict__ in, int R, int C,
                             unsigned short* __restrict__ out) {
  __shared__ float tile[32][33];
  int c0 = blockIdx.x * 32, r0 = blockIdx.y * 32;
  int tx = threadIdx.x, ty = threadIdx.y;
#pragma unroll
  for (int i = 0; i < 32; i += 8)
    tile[ty + i][tx] = in[(long)(r0 + ty + i) * C + c0 + tx];
  __syncthreads();
#pragma unroll
  for (int i = 0; i < 32; i += 8)
    out[(long)(c0 + ty + i) * R + r0 + tx] = f2bf(tile[tx][ty + i]);
}

// ---------------- 128x128 compose GEMM (r0-proven, 2-phase) ---------------
// C = A @ W^T. 4 waves, 64x64/wave, BK=32, global_load_lds staging.
// CE: 0 = plain write, 1 = also write transposed copy Ct[c*2048+row],
//     2 = accumulate into existing C.
enum { CE_PLAIN = 0, CE_WT = 1, CE_ACC = 2 };

template <int CE>
__global__ __launch_bounds__(256)
void compose_kernel(const unsigned short* __restrict__ A, int lda,
                    const unsigned short* __restrict__ W, int ldw,
                    unsigned short* C, int ldc,
                    unsigned short* Ct, long ctoff,
                    int K, int nmt,
                    int pairBase, long aoff, long woff, long coff) {
  constexpr int BK = 32;
  __shared__ unsigned short sA[128 * BK];
  __shared__ unsigned short sB[128 * BK];
  const int tid  = threadIdx.x;
  const int lane = tid & 63;
  const int wave = tid >> 6;
  const int wr = (wave >> 1) * 64;
  const int wc = (wave & 1) * 64;

  int bid = blockIdx.x;
  if (bid >= pairBase) {
    bid -= pairBase;
    A += aoff; W += woff; C += coff; Ct += ctoff;
  }
  const long tileM = (long)(bid % nmt) * 128;
  const long tileN = (long)(bid / nmt) * 128;

  const unsigned short* gA = A + (tileM + (tid >> 2)) * (long)lda + (tid & 3) * 8;
  const unsigned short* gB = W + (tileN + (tid >> 2)) * (long)ldw + (tid & 3) * 8;
  unsigned short* lA = sA + wave * 512;
  unsigned short* lB = sB + wave * 512;

  f32x4 acc[4][4] = {};
  const int fr = lane & 15;
  const int kb = (lane >> 4) * 8;

  for (int k0 = 0; k0 < K; k0 += BK) {
    __builtin_amdgcn_global_load_lds(
        (const __attribute__((address_space(1))) void*)(gA + k0),
        (__attribute__((address_space(3))) void*)(lA), 16, 0, 0);
    __builtin_amdgcn_global_load_lds(
        (const __attribute__((address_space(1))) void*)(gA + k0 + 64 * (long)lda),
        (__attribute__((address_space(3))) void*)(lA + 2048), 16, 0, 0);
    __builtin_amdgcn_global_load_lds(
        (const __attribute__((address_space(1))) void*)(gB + k0),
        (__attribute__((address_space(3))) void*)(lB), 16, 0, 0);
    __builtin_amdgcn_global_load_lds(
        (const __attribute__((address_space(1))) void*)(gB + k0 + 64 * (long)ldw),
        (__attribute__((address_space(3))) void*)(lB + 2048), 16, 0, 0);
    __syncthreads();

    short8 aF[4], bF[4];
#pragma unroll
    for (int m = 0; m < 4; ++m)
      aF[m] = *(const short8*)&sA[(wr + m * 16 + fr) * BK + kb];
#pragma unroll
    for (int n = 0; n < 4; ++n)
      bF[n] = *(const short8*)&sB[(wc + n * 16 + fr) * BK + kb];
#pragma unroll
    for (int m = 0; m < 4; ++m)
#pragma unroll
      for (int n = 0; n < 4; ++n)
        acc[m][n] = __builtin_amdgcn_mfma_f32_16x16x32_bf16(aF[m], bF[n], acc[m][n], 0, 0, 0);
    __syncthreads();
  }

  const int cr = (lane >> 4) * 4;
  const int cc = lane & 15;
#pragma unroll
  for (int m = 0; m < 4; ++m) {
    long r0 = tileM + wr + m * 16 + cr;
#pragma unroll
    for (int n = 0; n < 4; ++n) {
      long c = tileN + wc + n * 16 + cc;
#pragma unroll
      for (int r = 0; r < 4; ++r) {
        long idx = (r0 + r) * (long)ldc + c;
        float v = acc[m][n][r];
        if constexpr (CE == CE_ACC) v += bf2f(C[idx]);
        unsigned short bv = f2bf(v);
        C[idx] = bv;
        if constexpr (CE == CE_WT) Ct[c * 2048 + (r0 + r)] = bv;
      }
    }
  }
}

// ---------------- 256x256 bf16 GEMM, 8-phase (r6-proven schedule) ---------
enum { EPI_BIAS = 0, EPI_GATE = 2, EPI_LNF32 = 4 };

#define VMW(N) asm volatile("s_waitcnt vmcnt(" #N ")" ::: "memory")
#define SBAR() __builtin_amdgcn_s_barrier()
#define SCB() __builtin_amdgcn_sched_barrier(0)

#define STG(D, OP, HALF, PTR, LD8)                                            \
  { char* lp_ = (char*)smem + ((D)*65536 + (OP)*32768 + (HALF)*16384 + w*2048); \
    __builtin_amdgcn_global_load_lds(                                         \
        (const __attribute__((address_space(1))) void*)(PTR),                 \
        (__attribute__((address_space(3))) void*)lp_, 16, 0, 0);              \
    __builtin_amdgcn_global_load_lds(                                         \
        (const __attribute__((address_space(1))) void*)((PTR) + (LD8)),       \
        (__attribute__((address_space(3))) void*)(lp_ + 1024), 16, 0, 0);     \
    (PTR) += 64; }
#define NOSTG ((void)0)

#define RDA(D, KK) ((KK) ? ((D) ? pA11 : pA01) : ((D) ? pA10 : pA00))
#define RDB(D, KK) ((KK) ? ((D) ? pB11 : pB01) : ((D) ? pB10 : pB00))

template <int EPI, int SWZ>
__global__ __launch_bounds__(512, 2)
void gemm8p_kernel(const unsigned short* __restrict__ A, int lda,
                   const unsigned short* __restrict__ W, int ldw,
                   int K, int ldc, int nmt,
                   const float* __restrict__ bias,
                   const float* __restrict__ bias2,
                   const unsigned short* Xg,
                   const unsigned short* Xc, int ldx,
                   const float2* __restrict__ stats,
                   void* Cv) {
  __shared__ unsigned short smem[65536];  // 128 KB

  const int tid = threadIdx.x, lane = tid & 63, w = tid >> 6;
  const int wm = w >> 2, wn = w & 3;

  int bid = blockIdx.x;
  int mt, nt;
  if (SWZ) {  // 512 blocks: XCD x owns mt [x*8, x*8+8), sweeps 8 nt
    const int xcd = bid & 7, seq = bid >> 3;
    nt = seq >> 3;
    mt = xcd * 8 + (seq & 7);
  } else {
    mt = bid % nmt;
    nt = bid / nmt;
  }
  const long tileM = (long)mt * 256, tileN = (long)nt * 256;

  const int sRow = w * 16 + (lane >> 3);
  const int sCol = (((lane & 7) ^ ((lane >> 3) & 7)) * 8);
  const unsigned short* pSA0 = A + (tileM + sRow) * (long)lda + sCol;
  const unsigned short* pSA1 = pSA0 + 128 * (long)lda;
  const unsigned short* pSB0 = W + (tileN + sRow) * (long)ldw + sCol;
  const unsigned short* pSB1 = pSB0 + 128 * (long)ldw;
  const long lda8 = 8 * (long)lda, ldw8 = 8 * (long)ldw;

  const int fr = lane & 15, kc = lane >> 4, l7 = lane & 7;
  const char* pA00 = (const char*)smem + (wm * 16 + fr) * 128 + ((kc) ^ l7) * 16;
  const char* pA01 = (const char*)smem + (wm * 16 + fr) * 128 + ((4 + kc) ^ l7) * 16;
  const char* pA10 = pA00 + 65536;
  const char* pA11 = pA01 + 65536;
  const char* pB00 = (const char*)smem + 32768 + (wn * 16 + fr) * 128 + ((kc) ^ l7) * 16;
  const char* pB01 = (const char*)smem + 32768 + (wn * 16 + fr) * 128 + ((4 + kc) ^ l7) * 16;
  const char* pB10 = pB00 + 65536;
  const char* pB11 = pB01 + 65536;

  f32x4 acc[8][4] = {};
  short8 aH[4][2];
  short8 bqS[2][2][2];

#define PHASE(D, MQ, NQ, LA, LB, STGX)                                        \
  {                                                                           \
    if (LA) {                                                                 \
      _Pragma("unroll") for (int mi = 0; mi < 4; ++mi) {                      \
        aH[mi][0] = *(const short8*)(RDA(D, 0) + (MQ)*16384 + mi * 4096);     \
        aH[mi][1] = *(const short8*)(RDA(D, 1) + (MQ)*16384 + mi * 4096);     \
      }                                                                       \
    }                                                                         \
    if (LB) {                                                                 \
      _Pragma("unroll") for (int ni = 0; ni < 2; ++ni) {                      \
        bqS[NQ][ni][0] = *(const short8*)(RDB(D, 0) + (NQ)*16384 + ni * 8192);\
        bqS[NQ][ni][1] = *(const short8*)(RDB(D, 1) + (NQ)*16384 + ni * 8192);\
      }                                                                       \
    }                                                                         \
    STGX;                                                                     \
    SCB();                                                                    \
    __builtin_amdgcn_s_setprio(1);                                            \
    _Pragma("unroll") for (int mi = 0; mi < 4; ++mi)                          \
    _Pragma("unroll") for (int ni = 0; ni < 2; ++ni) {                        \
      acc[(MQ)*4+mi][(NQ)*2+ni] = __builtin_amdgcn_mfma_f32_16x16x32_bf16(    \
          aH[mi][0], bqS[NQ][ni][0], acc[(MQ)*4+mi][(NQ)*2+ni], 0, 0, 0);     \
      acc[(MQ)*4+mi][(NQ)*2+ni] = __builtin_amdgcn_mfma_f32_16x16x32_bf16(    \
          aH[mi][1], bqS[NQ][ni][1], acc[(MQ)*4+mi][(NQ)*2+ni], 0, 0, 0);     \
    }                                                                         \
    __builtin_amdgcn_s_setprio(0);                                            \
    SCB();                                                                    \
  }

  // ---- prologue: stage both K-tiles (steady-state FIFO order) ------------
  STG(0, 0, 0, pSA0, lda8);
  STG(0, 1, 0, pSB0, ldw8);
  STG(0, 1, 1, pSB1, ldw8);
  STG(0, 0, 1, pSA1, lda8);
  STG(1, 0, 0, pSA0, lda8);
  STG(1, 1, 0, pSB0, ldw8);
  STG(1, 1, 1, pSB1, ldw8);
  STG(1, 0, 1, pSA1, lda8);
  VMW(12);
  SBAR();

  const int NIT = K / 128;
  for (int it = 0; it < NIT - 1; ++it) {
    PHASE(0, 0, 0, 1, 1, NOSTG);                               VMW(10); SBAR();
    PHASE(0, 0, 1, 0, 1, STG(0, 0, 0, pSA0, lda8);
                         STG(0, 1, 0, pSB0, ldw8));            VMW(12); SBAR();
    PHASE(0, 1, 0, 1, 0, STG(0, 1, 1, pSB1, ldw8));                     SBAR();
    PHASE(0, 1, 1, 0, 0, STG(0, 0, 1, pSA1, lda8));            VMW(12); SBAR();
    PHASE(1, 0, 0, 1, 1, NOSTG);                               VMW(10); SBAR();
    PHASE(1, 0, 1, 0, 1, STG(1, 0, 0, pSA0, lda8);
                         STG(1, 1, 0, pSB0, ldw8));            VMW(12); SBAR();
    PHASE(1, 1, 0, 1, 0, STG(1, 1, 1, pSB1, ldw8));                     SBAR();
    PHASE(1, 1, 1, 0, 0, STG(1, 0, 1, pSA1, lda8));            VMW(12); SBAR();
  }
  {  // peeled drain iteration
    PHASE(0, 0, 0, 1, 1, NOSTG); VMW(10); SBAR();
    PHASE(0, 0, 1, 0, 1, NOSTG); VMW(8);  SBAR();
    PHASE(0, 1, 0, 1, 0, NOSTG);          SBAR();
    PHASE(0, 1, 1, 0, 0, NOSTG); VMW(4);  SBAR();
    PHASE(1, 0, 0, 1, 1, NOSTG); VMW(2);  SBAR();
    PHASE(1, 0, 1, 0, 1, NOSTG); VMW(0);  SBAR();
    PHASE(1, 1, 0, 1, 0, NOSTG);          SBAR();
    PHASE(1, 1, 1, 0, 0, NOSTG);
  }
#undef PHASE

  // ---- epilogue: C/D layout col = lane&15, row = (lane>>4)*4 + reg --------
  const int cr = (lane >> 4) * 4;
  const int cc = lane & 15;
#pragma unroll
  for (int m = 0; m < 8; ++m) {
    long rr = tileM + (m >> 2) * 128 + (m & 3) * 32 + wm * 16 + cr;
#pragma unroll
    for (int n = 0; n < 4; ++n) {
      long c = tileN + (n >> 1) * 128 + (n & 1) * 64 + wn * 16 + cc;
      float b1 = bias ? bias[c] : 0.0f;
      float b2 = bias2 ? bias2[c] : 0.0f;
#pragma unroll
      for (int r = 0; r < 4; ++r) {
        long row = rr + r;
        long idx = row * (long)ldc + c;
        float v = acc[m][n][r];
        if constexpr (EPI == EPI_BIAS) {
          ((unsigned short*)Cv)[idx] = f2bf(v + b1 + b2);
        }
        if constexpr (EPI == EPI_GATE) {
          float gt = 1.0f / (1.0f + expf(-(v + b1)));
          long xix = row * (long)ldx + c;
          float gv = bf2f(Xg[xix]);   // g (read BEFORE aliased write below)
          float cvv = bf2f(Xc[xix]);  // cross
          ((unsigned short*)Cv)[idx] = f2bf(gt * gv + (1.0f - gt) * cvv + gv);
        }
        if constexpr (EPI == EPI_LNF32) {
          float2 st = stats[row];  // (mu, rstd)
          ((float*)Cv)[idx] = v * st.y - st.y * st.x * b1 + b2;
        }
      }
    }
  }
}

// ---------------- per-row LN stats over 2048 cols -------------------------
__global__ __launch_bounds__(256) void lnstats_kernel(
    const unsigned short* __restrict__ in, float2* __restrict__ stats) {
  const int row = blockIdx.x;
  const int t = threadIdx.x, lane = t & 63, wave = t >> 6;
  short8 v8 = *(const short8*)&in[(long)row * 2048 + t * 8];
  float s = 0.f, s2 = 0.f;
#pragma unroll
  for (int j = 0; j < 8; ++j) {
    float x = bf2f((unsigned short)v8[j]);
    s += x; s2 += x * x;
  }
#pragma unroll
  for (int off = 1; off < 64; off <<= 1) {
    s  += __shfl_xor(s, off);
    s2 += __shfl_xor(s2, off);
  }
  __shared__ float red[8];
  if (lane == 0) { red[wave] = s; red[4 + wave] = s2; }
  __syncthreads();
  if (t == 0) {
    float ts  = red[0] + red[1] + red[2] + red[3];
    float ts2 = red[4] + red[5] + red[6] + red[7];
    float mean = ts * (1.0f / 2048.0f);
    float var  = ts2 * (1.0f / 2048.0f) - mean * mean;
    stats[row] = make_float2(mean, rsqrtf(var + 1e-5f));
  }
}

// block-reduce helper: 256 threads, returns total on t==0
__device__ __forceinline__ float blkRed(float s, float* red, int lane, int wave) {
#pragma unroll
  for (int off = 1; off < 64; off <<= 1) s += __shfl_xor(s, off);
  if (lane == 0) red[wave] = s;
  __syncthreads();
  return red[0] + red[1] + red[2] + red[3];
}

// bcV[c] = o1b+o2b + wO1b[c]·bv1 + wO2b[c]·bv2 + Wc1[c]·tp_b + Wc2[c]·gp_b
__global__ __launch_bounds__(256) void biascompP_kernel(
    const unsigned short* __restrict__ wO1b, const unsigned short* __restrict__ wO2b,
    const unsigned short* __restrict__ Wc1, const unsigned short* __restrict__ Wc2,
    const float* __restrict__ bv1, const float* __restrict__ bv2,
    const float* __restrict__ tpb, const float* __restrict__ gpb,
    const float* __restrict__ o1b, const float* __restrict__ o2b,
    float* __restrict__ bcV) {
  __shared__ float red[4];
  int c = blockIdx.x, t = threadIdx.x, lane = t & 63, wave = t >> 6;
  int k = t * 8;
  float s = 0.f;
  short8 a1 = *(const short8*)(wO1b + (long)c * 2048 + k);
  short8 a2 = *(const short8*)(wO2b + (long)c * 2048 + k);
  short8 a3 = *(const short8*)(Wc1 + (long)c * 2048 + k);
  short8 a4 = *(const short8*)(Wc2 + (long)c * 2048 + k);
#pragma unroll
  for (int j = 0; j < 8; ++j)
    s += bf2f((unsigned short)a1[j]) * bv1[k + j]
       + bf2f((unsigned short)a2[j]) * bv2[k + j]
       + bf2f((unsigned short)a3[j]) * tpb[k + j]
       + bf2f((unsigned short)a4[j]) * gpb[k + j];
  float tot = blkRed(s, red, lane, wave);
  if (t == 0) bcV[c] = tot + o1b[c] + o2b[c];
}

// bgateV[n] = gate_b[n] + gw_g[n,:]·gp_b + gw_c[n,:]·bcV   (fp32 gate_w)
__global__ __launch_bounds__(256) void bgateP_kernel(
    const float* __restrict__ gate_w, const float* __restrict__ gate_b,
    const float* __restrict__ gpb, const float* __restrict__ bcV,
    float* __restrict__ bgateV) {
  __shared__ float red[4];
  int n = blockIdx.x, t = threadIdx.x, lane = t & 63, wave = t >> 6;
  const float* row = gate_w + (long)n * 4096;
  float s = 0.f;
  int k = t * 8;
#pragma unroll
  for (int j = 0; j < 8; ++j)
    s += row[k + j] * gpb[k + j] + row[2048 + k + j] * bcV[k + j];
  float tot = blkRed(s, red, lane, wave);
  if (t == 0) bgateV[n] = tot + gate_b[n];
}

// u[n] = rowsum(gamma-folded wLIN); v[n] = ln_beta·lin_w[n,:] + lin_b[n]
__global__ __launch_bounds__(256) void uvP_kernel(
    const unsigned short* __restrict__ wlinp, const float* __restrict__ lin_w,
    const float* __restrict__ ln_beta, const float* __restrict__ lin_b,
    float* __restrict__ uV, float* __restrict__ vV) {
  __shared__ float redu[4], redv[4];
  int n = blockIdx.x, t = threadIdx.x, lane = t & 63, wave = t >> 6;
  int k = t * 8;
  short8 a1 = *(const short8*)(wlinp + (long)n * 2048 + k);
  float u = 0.f, v = 0.f;
#pragma unroll
  for (int j = 0; j < 8; ++j) {
    u += bf2f((unsigned short)a1[j]);
    v += ln_beta[k + j] * lin_w[(long)n * 2048 + k + j];
  }
#pragma unroll
  for (int off = 1; off < 64; off <<= 1) {
    u += __shfl_xor(u, off);
    v += __shfl_xor(v, off);
  }
  if (lane == 0) { redu[wave] = u; redv[wave] = v; }
  __syncthreads();
  if (t == 0) {
    uV[n] = redu[0] + redu[1] + redu[2] + redu[3];
    vV[n] = redv[0] + redv[1] + redv[2] + redv[3] + lin_b[n];
  }
}

// --------------------------------------------------------------------------
extern "C" void kernel_launch(void* const* d_in, const int* in_sizes, int n_in,
                              void* d_out, int out_size, void* d_ws, size_t ws_size,
                              hipStream_t stream) {
  const float* graph    = (const float*)d_in[0];
  const float* temporal = (const float*)d_in[1];
  const float* gp_w  = (const float*)d_in[2];
  const float* gp_b  = (const float*)d_in[3];
  const float* tp_w  = (const float*)d_in[4];
  const float* tp_b  = (const float*)d_in[5];
  const float* in1_w = (const float*)d_in[6];
  const float* in1_b = (const float*)d_in[7];
  const float* out1_w = (const float*)d_in[8];
  const float* out1_b = (const float*)d_in[9];
  const float* in2_w = (const float*)d_in[10];
  const float* in2_b = (const float*)d_in[11];
  const float* out2_w = (const float*)d_in[12];
  const float* out2_b = (const float*)d_in[13];
  const float* gate_w = (const float*)d_in[14];
  const float* gate_b = (const float*)d_in[15];
  const float* ln_g  = (const float*)d_in[16];
  const float* ln_b  = (const float*)d_in[17];
  const float* lin_w = (const float*)d_in[18];
  const float* lin_b = (const float*)d_in[19];

  const int Bm = 16384, F = 2048, GD = 1024;
  const long BF = (long)Bm * F, FF = (long)F * F, FG = (long)F * GD;

  // ---- ws layout (~210 MB) ----
  unsigned short* TG    = (unsigned short*)d_ws;  // [16384][2048] = [t|g]
  unsigned short* Gbuf  = TG + BF;                // g; later preLN (aliased)
  unsigned short* Cbuf  = Gbuf + BF;              // cross
  unsigned short* wLIN  = Cbuf + BF;              // gamma-folded lin_w
  float* bcV    = (float*)(wLIN + FF);
  float* bgateV = bcV + F;
  float* uV     = bgateV + F;
  float* vV     = uV + F;
  float2* stats = (float2*)(vV + F);              // 16384 float2

  // ---- d_out scratch (~100 MB, dead before final GEMM writes d_out) ----
  unsigned short* DO      = (unsigned short*)d_out;
  unsigned short* wv1T    = DO;            // [2048][2048]
  unsigned short* wv2T    = wv1T + FF;
  unsigned short* tpT     = wv2T + FF;     // [1024][2048]
  unsigned short* gpT     = tpT + FG;
  unsigned short* Wc1     = gpT + FG;      // [2048][2048]
  unsigned short* Wc2     = Wc1 + FF;
  unsigned short* wO1b    = Wc2 + FF;
  unsigned short* wO2b    = wO1b + FF;
  unsigned short* wGATEb  = wO2b + FF;     // [2048][4096]
  unsigned short* wGP     = wGATEb + 2 * FF;  // [2048][1024]
  unsigned short* Wcross  = wGP + FG;      // [2048][2048]
  unsigned short* WcrossT = Wcross + FF;   // [2048][2048]
  unsigned short* Wgate   = WcrossT + FF;  // [2048][2048]

  auto conv = [&](const float* src, unsigned short* dst, long n) {
    conv_kernel<<<dim3((unsigned)(n / 8 / 256)), 256, 0, stream>>>(src, dst, (int)n);
  };
  // inputs -> TG = [temporal | graph]
  convcat_kernel<<<dim3((unsigned)(Bm * GD / 8 / 256)), 256, 0, stream>>>(
      temporal, TG, 0, Bm * GD);
  convcat_kernel<<<dim3((unsigned)(Bm * GD / 8 / 256)), 256, 0, stream>>>(
      graph, TG, GD, Bm * GD);
  conv(gp_w, wGP, FG);
  conv(out1_w, wO1b, FF);
  conv(out2_w, wO2b, FF);
  conv(gate_w, wGATEb, 2 * FF);
  convs_kernel<<<dim3((unsigned)(FF / 8 / 256)), 256, 0, stream>>>(lin_w, ln_g, wLIN, (int)FF);
  tconv_kernel<<<dim3(F / 32, F / 32), dim3(32, 8), 0, stream>>>(in1_w + 2 * FF, F, F, wv1T);
  tconv_kernel<<<dim3(F / 32, F / 32), dim3(32, 8), 0, stream>>>(in2_w + 2 * FF, F, F, wv2T);
  tconv_kernel<<<dim3(GD / 32, F / 32), dim3(32, 8), 0, stream>>>(tp_w, F, GD, tpT);
  tconv_kernel<<<dim3(GD / 32, F / 32), dim3(32, 8), 0, stream>>>(gp_w, F, GD, gpT);

  // C1 (pair, 512 blocks): Wc1 = wO1@wv1, Wc2 = wO2@wv2   [2048x2048] K=2048
  compose_kernel<CE_PLAIN><<<dim3(512), dim3(256), 0, stream>>>(
      wO1b, F, wv1T, F, Wc1, F, nullptr, 0, F, 16,
      256, wO2b - wO1b, wv2T - wv1T, Wc2 - Wc1);
  // C2 (pair, 256 blocks): Wcross = [Wc1@tp_w | Wc2@gp_w], + transposed copy
  compose_kernel<CE_WT><<<dim3(256), dim3(256), 0, stream>>>(
      Wc1, F, tpT, F, Wcross, F, WcrossT, (long)1024 * 2048, F, 16,
      128, Wc2 - Wc1, gpT - tpT, 1024);
  // composed cross-bias
  biascompP_kernel<<<dim3(F), dim3(256), 0, stream>>>(
      wO1b, wO2b, Wc1, Wc2, in1_b + 2 * F, in2_b + 2 * F, tp_b, gp_b,
      out1_b, out2_b, bcV);
  // C3a (256 blocks): Wgate = gw_c @ Wcross  (A = gw_c, W = WcrossT)
  compose_kernel<CE_PLAIN><<<dim3(256), dim3(256), 0, stream>>>(
      wGATEb + F, 2 * F, WcrossT, F, Wgate, F, nullptr, 0, F, 16,
      1 << 30, 0, 0, 0);
  // C3b (128 blocks): Wgate[:,1024:] += gw_g @ gp_w  (A = gw_g, W = gpT)
  compose_kernel<CE_ACC><<<dim3(128), dim3(256), 0, stream>>>(
      wGATEb, 2 * F, gpT, F, Wgate + GD, F, nullptr, 0, F, 16,
      1 << 30, 0, 0, 0);
  // composed gate bias + LN-fold vectors
  bgateP_kernel<<<dim3(F), dim3(256), 0, stream>>>(gate_w, gate_b, gp_b, bcV, bgateV);
  uvP_kernel<<<dim3(F), dim3(256), 0, stream>>>(wLIN, lin_w, ln_b, lin_b, uV, vV);

  dim3 blk(512), grid(512);
  // g = graph @ gp_w^T + gp_b          (K=1024) -> Gbuf
  gemm8p_kernel<EPI_BIAS, 1><<<grid, blk, 0, stream>>>(
      TG + GD, F, wGP, GD, GD, F, 0,
      gp_b, nullptr, nullptr, nullptr, 0, nullptr, Gbuf);
  // cross = TG @ Wcross^T + bcV        (K=2048) -> Cbuf
  gemm8p_kernel<EPI_BIAS, 1><<<grid, blk, 0, stream>>>(
      TG, F, Wcross, F, F, F, 0,
      bcV, nullptr, nullptr, nullptr, 0, nullptr, Cbuf);
  // preLN = gatefuse(TG @ Wgate^T + bgateV)  (K=2048) -> Gbuf (aliases Xg)
  gemm8p_kernel<EPI_GATE, 1><<<grid, blk, 0, stream>>>(
      TG, F, Wgate, F, F, F, 0,
      bgateV, nullptr, Gbuf, Cbuf, F, nullptr, Gbuf);
  // per-row LN stats
  lnstats_kernel<<<dim3(Bm), dim3(256), 0, stream>>>(Gbuf, stats);
  // out = rstd*(preLN @ wLIN^T) - rstd*mu*u + v   (K=2048, fp32) -> d_out
  gemm8p_kernel<EPI_LNF32, 1><<<grid, blk, 0, stream>>>(
      Gbuf, F, wLIN, F, F, F, 0,
      uV, vV, nullptr, nullptr, 0, stats, (void*)d_out);
}

// Round 9
// 806.879 us; speedup vs baseline: 2.6145x; 1.1060x over previous
//
#include <hip/hip_runtime.h>
#include <stdint.h>

typedef __attribute__((ext_vector_type(8))) short short8;
typedef __attribute__((ext_vector_type(4))) float f32x4;

__device__ __forceinline__ unsigned short f2bf(float f) {
  union { float f; uint32_t u; } v; v.f = f;
  uint32_t u = v.u;
  u += 0x7FFF + ((u >> 16) & 1);   // round-to-nearest-even
  return (unsigned short)(u >> 16);
}
__device__ __forceinline__ float bf2f(unsigned short h) {
  union { uint32_t u; float f; } v; v.u = ((uint32_t)h) << 16;
  return v.f;
}

// ---------------- convert fp32 -> bf16 (8 elems/thread) -------------------
__global__ void conv_kernel(const float* __restrict__ in,
                            unsigned short* __restrict__ out, int n) {
  long i = ((long)blockIdx.x * blockDim.x + threadIdx.x) * 8;
  if (i >= n) return;
  float4 a = *(const float4*)(in + i);
  float4 b = *(const float4*)(in + i + 4);
  short8 s;
  s[0] = (short)f2bf(a.x); s[1] = (short)f2bf(a.y);
  s[2] = (short)f2bf(a.z); s[3] = (short)f2bf(a.w);
  s[4] = (short)f2bf(b.x); s[5] = (short)f2bf(b.y);
  s[6] = (short)f2bf(b.z); s[7] = (short)f2bf(b.w);
  *(short8*)(out + i) = s;
}

// concat-convert: src [R][1024] fp32 -> dst[row][colbase + col] bf16, ldo=2048
__global__ void convcat_kernel(const float* __restrict__ in,
                               unsigned short* __restrict__ out,
                               int colbase, int n) {
  long i = ((long)blockIdx.x * blockDim.x + threadIdx.x) * 8;
  if (i >= n) return;
  float4 a = *(const float4*)(in + i);
  float4 b = *(const float4*)(in + i + 4);
  short8 s;
  s[0] = (short)f2bf(a.x); s[1] = (short)f2bf(a.y);
  s[2] = (short)f2bf(a.z); s[3] = (short)f2bf(a.w);
  s[4] = (short)f2bf(b.x); s[5] = (short)f2bf(b.y);
  s[6] = (short)f2bf(b.z); s[7] = (short)f2bf(b.w);
  long row = i >> 10, col = i & 1023;
  *(short8*)(out + row * 2048 + colbase + col) = s;
}

// convert with per-column scale fold: out[i] = bf16(in[i] * scale[i & 2047])
__global__ void convs_kernel(const float* __restrict__ in,
                             const float* __restrict__ scale,
                             unsigned short* __restrict__ out, int n) {
  long i = ((long)blockIdx.x * blockDim.x + threadIdx.x) * 8;
  if (i >= n) return;
  short8 s;
#pragma unroll
  for (int j = 0; j < 8; ++j)
    s[j] = (short)f2bf(in[i + j] * scale[(i + j) & 2047]);
  *(short8*)(out + i) = s;
}

// transpose-convert: out[C][R] = bf16(in[R][C]^T). block (32,8), grid (C/32, R/32)
__global__ void tconv_kernel(const float* __restrict__ in, int R, int C,
                             unsigned short* __restrict__ out) {
  __shared__ float tile[32][33];
  int c0 = blockIdx.x * 32, r0 = blockIdx.y * 32;
  int tx = threadIdx.x, ty = threadIdx.y;
#pragma unroll
  for (int i = 0; i < 32; i += 8)
    tile[ty + i][tx] = in[(long)(r0 + ty + i) * C + c0 + tx];
  __syncthreads();
#pragma unroll
  for (int i = 0; i < 32; i += 8)
    out[(long)(c0 + ty + i) * R + r0 + tx] = f2bf(tile[tx][ty + i]);
}

// ---------------- 128x128 compose GEMM (r0-proven, 2-phase) ---------------
enum { CE_PLAIN = 0, CE_WT = 1, CE_ACC = 2 };

template <int CE>
__global__ __launch_bounds__(256)
void compose_kernel(const unsigned short* __restrict__ A, int lda,
                    const unsigned short* __restrict__ W, int ldw,
                    unsigned short* C, int ldc,
                    unsigned short* Ct, long ctoff,
                    int K, int nmt,
                    int pairBase, long aoff, long woff, long coff) {
  constexpr int BK = 32;
  __shared__ unsigned short sA[128 * BK];
  __shared__ unsigned short sB[128 * BK];
  const int tid  = threadIdx.x;
  const int lane = tid & 63;
  const int wave = tid >> 6;
  const int wr = (wave >> 1) * 64;
  const int wc = (wave & 1) * 64;

  int bid = blockIdx.x;
  if (bid >= pairBase) {
    bid -= pairBase;
    A += aoff; W += woff; C += coff; Ct += ctoff;
  }
  const long tileM = (long)(bid % nmt) * 128;
  const long tileN = (long)(bid / nmt) * 128;

  const unsigned short* gA = A + (tileM + (tid >> 2)) * (long)lda + (tid & 3) * 8;
  const unsigned short* gB = W + (tileN + (tid >> 2)) * (long)ldw + (tid & 3) * 8;
  unsigned short* lA = sA + wave * 512;
  unsigned short* lB = sB + wave * 512;

  f32x4 acc[4][4] = {};
  const int fr = lane & 15;
  const int kb = (lane >> 4) * 8;

  for (int k0 = 0; k0 < K; k0 += BK) {
    __builtin_amdgcn_global_load_lds(
        (const __attribute__((address_space(1))) void*)(gA + k0),
        (__attribute__((address_space(3))) void*)(lA), 16, 0, 0);
    __builtin_amdgcn_global_load_lds(
        (const __attribute__((address_space(1))) void*)(gA + k0 + 64 * (long)lda),
        (__attribute__((address_space(3))) void*)(lA + 2048), 16, 0, 0);
    __builtin_amdgcn_global_load_lds(
        (const __attribute__((address_space(1))) void*)(gB + k0),
        (__attribute__((address_space(3))) void*)(lB), 16, 0, 0);
    __builtin_amdgcn_global_load_lds(
        (const __attribute__((address_space(1))) void*)(gB + k0 + 64 * (long)ldw),
        (__attribute__((address_space(3))) void*)(lB + 2048), 16, 0, 0);
    __syncthreads();

    short8 aF[4], bF[4];
#pragma unroll
    for (int m = 0; m < 4; ++m)
      aF[m] = *(const short8*)&sA[(wr + m * 16 + fr) * BK + kb];
#pragma unroll
    for (int n = 0; n < 4; ++n)
      bF[n] = *(const short8*)&sB[(wc + n * 16 + fr) * BK + kb];
#pragma unroll
    for (int m = 0; m < 4; ++m)
#pragma unroll
      for (int n = 0; n < 4; ++n)
        acc[m][n] = __builtin_amdgcn_mfma_f32_16x16x32_bf16(aF[m], bF[n], acc[m][n], 0, 0, 0);
    __syncthreads();
  }

  const int cr = (lane >> 4) * 4;
  const int cc = lane & 15;
#pragma unroll
  for (int m = 0; m < 4; ++m) {
    long r0 = tileM + wr + m * 16 + cr;
#pragma unroll
    for (int n = 0; n < 4; ++n) {
      long c = tileN + wc + n * 16 + cc;
#pragma unroll
      for (int r = 0; r < 4; ++r) {
        long idx = (r0 + r) * (long)ldc + c;
        float v = acc[m][n][r];
        if constexpr (CE == CE_ACC) v += bf2f(C[idx]);
        unsigned short bv = f2bf(v);
        C[idx] = bv;
        if constexpr (CE == CE_WT) Ct[c * 2048 + (r0 + r)] = bv;
      }
    }
  }
}

// ---------------- 256x256 bf16 GEMM, 8-phase (r6-proven schedule) ---------
enum { EPI_BIAS = 0, EPI_LNF32 = 4 };

#define VMW(N) asm volatile("s_waitcnt vmcnt(" #N ")" ::: "memory")
#define SBAR() __builtin_amdgcn_s_barrier()
#define SCB() __builtin_amdgcn_sched_barrier(0)

#define STG(D, OP, HALF, PTR, LD8)                                            \
  { char* lp_ = (char*)smem + ((D)*65536 + (OP)*32768 + (HALF)*16384 + w*2048); \
    __builtin_amdgcn_global_load_lds(                                         \
        (const __attribute__((address_space(1))) void*)(PTR),                 \
        (__attribute__((address_space(3))) void*)lp_, 16, 0, 0);              \
    __builtin_amdgcn_global_load_lds(                                         \
        (const __attribute__((address_space(1))) void*)((PTR) + (LD8)),       \
        (__attribute__((address_space(3))) void*)(lp_ + 1024), 16, 0, 0);     \
    (PTR) += 64; }
#define NOSTG ((void)0)

#define RDA(D, KK) ((KK) ? ((D) ? pA11 : pA01) : ((D) ? pA10 : pA00))
#define RDB(D, KK) ((KK) ? ((D) ? pB11 : pB01) : ((D) ? pB10 : pB00))

template <int EPI, int SWZ>
__global__ __launch_bounds__(512, 2)
void gemm8p_kernel(const unsigned short* __restrict__ A, int lda,
                   const unsigned short* __restrict__ W, int ldw,
                   int K, int ldc, int nmt,
                   const float* __restrict__ bias,
                   const float* __restrict__ bias2,
                   const float2* __restrict__ stats,
                   void* Cv) {
  __shared__ unsigned short smem[65536];  // 128 KB

  const int tid = threadIdx.x, lane = tid & 63, w = tid >> 6;
  const int wm = w >> 2, wn = w & 3;

  int bid = blockIdx.x;
  int mt, nt;
  if (SWZ) {  // XCD x owns mt [x*8, x*8+8), sweeps all nt (any grid = 512*k)
    const int xcd = bid & 7, seq = bid >> 3;
    nt = seq >> 3;
    mt = xcd * 8 + (seq & 7);
  } else {
    mt = bid % nmt;
    nt = bid / nmt;
  }
  const long tileM = (long)mt * 256, tileN = (long)nt * 256;

  const int sRow = w * 16 + (lane >> 3);
  const int sCol = (((lane & 7) ^ ((lane >> 3) & 7)) * 8);
  const unsigned short* pSA0 = A + (tileM + sRow) * (long)lda + sCol;
  const unsigned short* pSA1 = pSA0 + 128 * (long)lda;
  const unsigned short* pSB0 = W + (tileN + sRow) * (long)ldw + sCol;
  const unsigned short* pSB1 = pSB0 + 128 * (long)ldw;
  const long lda8 = 8 * (long)lda, ldw8 = 8 * (long)ldw;

  const int fr = lane & 15, kc = lane >> 4, l7 = lane & 7;
  const char* pA00 = (const char*)smem + (wm * 16 + fr) * 128 + ((kc) ^ l7) * 16;
  const char* pA01 = (const char*)smem + (wm * 16 + fr) * 128 + ((4 + kc) ^ l7) * 16;
  const char* pA10 = pA00 + 65536;
  const char* pA11 = pA01 + 65536;
  const char* pB00 = (const char*)smem + 32768 + (wn * 16 + fr) * 128 + ((kc) ^ l7) * 16;
  const char* pB01 = (const char*)smem + 32768 + (wn * 16 + fr) * 128 + ((4 + kc) ^ l7) * 16;
  const char* pB10 = pB00 + 65536;
  const char* pB11 = pB01 + 65536;

  f32x4 acc[8][4] = {};
  short8 aH[4][2];
  short8 bqS[2][2][2];

#define PHASE(D, MQ, NQ, LA, LB, STGX)                                        \
  {                                                                           \
    if (LA) {                                                                 \
      _Pragma("unroll") for (int mi = 0; mi < 4; ++mi) {                      \
        aH[mi][0] = *(const short8*)(RDA(D, 0) + (MQ)*16384 + mi * 4096);     \
        aH[mi][1] = *(const short8*)(RDA(D, 1) + (MQ)*16384 + mi * 4096);     \
      }                                                                       \
    }                                                                         \
    if (LB) {                                                                 \
      _Pragma("unroll") for (int ni = 0; ni < 2; ++ni) {                      \
        bqS[NQ][ni][0] = *(const short8*)(RDB(D, 0) + (NQ)*16384 + ni * 8192);\
        bqS[NQ][ni][1] = *(const short8*)(RDB(D, 1) + (NQ)*16384 + ni * 8192);\
      }                                                                       \
    }                                                                         \
    STGX;                                                                     \
    SCB();                                                                    \
    __builtin_amdgcn_s_setprio(1);                                            \
    _Pragma("unroll") for (int mi = 0; mi < 4; ++mi)                          \
    _Pragma("unroll") for (int ni = 0; ni < 2; ++ni) {                        \
      acc[(MQ)*4+mi][(NQ)*2+ni] = __builtin_amdgcn_mfma_f32_16x16x32_bf16(    \
          aH[mi][0], bqS[NQ][ni][0], acc[(MQ)*4+mi][(NQ)*2+ni], 0, 0, 0);     \
      acc[(MQ)*4+mi][(NQ)*2+ni] = __builtin_amdgcn_mfma_f32_16x16x32_bf16(    \
          aH[mi][1], bqS[NQ][ni][1], acc[(MQ)*4+mi][(NQ)*2+ni], 0, 0, 0);     \
    }                                                                         \
    __builtin_amdgcn_s_setprio(0);                                            \
    SCB();                                                                    \
  }

  // ---- prologue: stage both K-tiles (steady-state FIFO order) ------------
  STG(0, 0, 0, pSA0, lda8);
  STG(0, 1, 0, pSB0, ldw8);
  STG(0, 1, 1, pSB1, ldw8);
  STG(0, 0, 1, pSA1, lda8);
  STG(1, 0, 0, pSA0, lda8);
  STG(1, 1, 0, pSB0, ldw8);
  STG(1, 1, 1, pSB1, ldw8);
  STG(1, 0, 1, pSA1, lda8);
  VMW(12);
  SBAR();

  const int NIT = K / 128;
  for (int it = 0; it < NIT - 1; ++it) {
    PHASE(0, 0, 0, 1, 1, NOSTG);                               VMW(10); SBAR();
    PHASE(0, 0, 1, 0, 1, STG(0, 0, 0, pSA0, lda8);
                         STG(0, 1, 0, pSB0, ldw8));            VMW(12); SBAR();
    PHASE(0, 1, 0, 1, 0, STG(0, 1, 1, pSB1, ldw8));                     SBAR();
    PHASE(0, 1, 1, 0, 0, STG(0, 0, 1, pSA1, lda8));            VMW(12); SBAR();
    PHASE(1, 0, 0, 1, 1, NOSTG);                               VMW(10); SBAR();
    PHASE(1, 0, 1, 0, 1, STG(1, 0, 0, pSA0, lda8);
                         STG(1, 1, 0, pSB0, ldw8));            VMW(12); SBAR();
    PHASE(1, 1, 0, 1, 0, STG(1, 1, 1, pSB1, ldw8));                     SBAR();
    PHASE(1, 1, 1, 0, 0, STG(1, 0, 1, pSA1, lda8));            VMW(12); SBAR();
  }
  {  // peeled drain iteration
    PHASE(0, 0, 0, 1, 1, NOSTG); VMW(10); SBAR();
    PHASE(0, 0, 1, 0, 1, NOSTG); VMW(8);  SBAR();
    PHASE(0, 1, 0, 1, 0, NOSTG);          SBAR();
    PHASE(0, 1, 1, 0, 0, NOSTG); VMW(4);  SBAR();
    PHASE(1, 0, 0, 1, 1, NOSTG); VMW(2);  SBAR();
    PHASE(1, 0, 1, 0, 1, NOSTG); VMW(0);  SBAR();
    PHASE(1, 1, 0, 1, 0, NOSTG);          SBAR();
    PHASE(1, 1, 1, 0, 0, NOSTG);
  }
#undef PHASE

  // ---- epilogue: C/D layout col = lane&15, row = (lane>>4)*4 + reg --------
  const int cr = (lane >> 4) * 4;
  const int cc = lane & 15;
#pragma unroll
  for (int m = 0; m < 8; ++m) {
    long rr = tileM + (m >> 2) * 128 + (m & 3) * 32 + wm * 16 + cr;
#pragma unroll
    for (int n = 0; n < 4; ++n) {
      long c = tileN + (n >> 1) * 128 + (n & 1) * 64 + wn * 16 + cc;
      float b1 = bias ? bias[c] : 0.0f;
      float b2 = bias2 ? bias2[c] : 0.0f;
#pragma unroll
      for (int r = 0; r < 4; ++r) {
        long row = rr + r;
        long idx = row * (long)ldc + c;
        float v = acc[m][n][r];
        if constexpr (EPI == EPI_BIAS) {
          ((unsigned short*)Cv)[idx] = f2bf(v + b1 + b2);
        }
        if constexpr (EPI == EPI_LNF32) {
          float2 st = stats[row];  // (mu, rstd)
          ((float*)Cv)[idx] = v * st.y - st.y * st.x * b1 + b2;
        }
      }
    }
  }
}

// ---- fuse gate + residual + LN stats, streaming, one row per block -------
// CL row: [cross(0:2048) | logits(2048:4096)]; g row: Gbuf.
// pre = sig(L)*g + (1-sig(L))*cross + g  (bf16-rounded), stats on rounded.
__global__ __launch_bounds__(256) void fusestats_kernel(
    const unsigned short* __restrict__ CL, const unsigned short* __restrict__ G,
    unsigned short* __restrict__ PL, float2* __restrict__ stats) {
  const int row = blockIdx.x;
  const int t = threadIdx.x, lane = t & 63, wave = t >> 6;
  short8 xc = *(const short8*)&CL[(long)row * 4096 + t * 8];
  short8 xl = *(const short8*)&CL[(long)row * 4096 + 2048 + t * 8];
  short8 xg = *(const short8*)&G[(long)row * 2048 + t * 8];
  short8 o8;
  float s = 0.f, s2 = 0.f;
#pragma unroll
  for (int j = 0; j < 8; ++j) {
    float cv = bf2f((unsigned short)xc[j]);
    float lv = bf2f((unsigned short)xl[j]);
    float gv = bf2f((unsigned short)xg[j]);
    float gt = 1.0f / (1.0f + expf(-lv));
    unsigned short pb = f2bf(gt * gv + (1.0f - gt) * cv + gv);
    o8[j] = (short)pb;
    float x = bf2f(pb);
    s += x; s2 += x * x;
  }
  *(short8*)(PL + (long)row * 2048 + t * 8) = o8;
#pragma unroll
  for (int off = 1; off < 64; off <<= 1) {
    s  += __shfl_xor(s, off);
    s2 += __shfl_xor(s2, off);
  }
  __shared__ float red[8];
  if (lane == 0) { red[wave] = s; red[4 + wave] = s2; }
  __syncthreads();
  if (t == 0) {
    float ts  = red[0] + red[1] + red[2] + red[3];
    float ts2 = red[4] + red[5] + red[6] + red[7];
    float mean = ts * (1.0f / 2048.0f);
    float var  = ts2 * (1.0f / 2048.0f) - mean * mean;
    stats[row] = make_float2(mean, rsqrtf(var + 1e-5f));
  }
}

// block-reduce helper: 256 threads, returns total on t==0
__device__ __forceinline__ float blkRed(float s, float* red, int lane, int wave) {
#pragma unroll
  for (int off = 1; off < 64; off <<= 1) s += __shfl_xor(s, off);
  if (lane == 0) red[wave] = s;
  __syncthreads();
  return red[0] + red[1] + red[2] + red[3];
}

// bcV[c] = o1b+o2b + wO1b[c]·bv1 + wO2b[c]·bv2 + Wc1[c]·tp_b + Wc2[c]·gp_b
__global__ __launch_bounds__(256) void biascompP_kernel(
    const unsigned short* __restrict__ wO1b, const unsigned short* __restrict__ wO2b,
    const unsigned short* __restrict__ Wc1, const unsigned short* __restrict__ Wc2,
    const float* __restrict__ bv1, const float* __restrict__ bv2,
    const float* __restrict__ tpb, const float* __restrict__ gpb,
    const float* __restrict__ o1b, const float* __restrict__ o2b,
    float* __restrict__ bcV) {
  __shared__ float red[4];
  int c = blockIdx.x, t = threadIdx.x, lane = t & 63, wave = t >> 6;
  int k = t * 8;
  float s = 0.f;
  short8 a1 = *(const short8*)(wO1b + (long)c * 2048 + k);
  short8 a2 = *(const short8*)(wO2b + (long)c * 2048 + k);
  short8 a3 = *(const short8*)(Wc1 + (long)c * 2048 + k);
  short8 a4 = *(const short8*)(Wc2 + (long)c * 2048 + k);
#pragma unroll
  for (int j = 0; j < 8; ++j)
    s += bf2f((unsigned short)a1[j]) * bv1[k + j]
       + bf2f((unsigned short)a2[j]) * bv2[k + j]
       + bf2f((unsigned short)a3[j]) * tpb[k + j]
       + bf2f((unsigned short)a4[j]) * gpb[k + j];
  float tot = blkRed(s, red, lane, wave);
  if (t == 0) bcV[c] = tot + o1b[c] + o2b[c];
}

// bgateV[n] = gate_b[n] + gw_g[n,:]·gp_b + gw_c[n,:]·bcV   (fp32 gate_w)
__global__ __launch_bounds__(256) void bgateP_kernel(
    const float* __restrict__ gate_w, const float* __restrict__ gate_b,
    const float* __restrict__ gpb, const float* __restrict__ bcV,
    float* __restrict__ bgateV) {
  __shared__ float red[4];
  int n = blockIdx.x, t = threadIdx.x, lane = t & 63, wave = t >> 6;
  const float* row = gate_w + (long)n * 4096;
  float s = 0.f;
  int k = t * 8;
#pragma unroll
  for (int j = 0; j < 8; ++j)
    s += row[k + j] * gpb[k + j] + row[2048 + k + j] * bcV[k + j];
  float tot = blkRed(s, red, lane, wave);
  if (t == 0) bgateV[n] = tot + gate_b[n];
}

// u[n] = rowsum(gamma-folded wLIN); v[n] = ln_beta·lin_w[n,:] + lin_b[n]
__global__ __launch_bounds__(256) void uvP_kernel(
    const unsigned short* __restrict__ wlinp, const float* __restrict__ lin_w,
    const float* __restrict__ ln_beta, const float* __restrict__ lin_b,
    float* __restrict__ uV, float* __restrict__ vV) {
  __shared__ float redu[4], redv[4];
  int n = blockIdx.x, t = threadIdx.x, lane = t & 63, wave = t >> 6;
  int k = t * 8;
  short8 a1 = *(const short8*)(wlinp + (long)n * 2048 + k);
  float u = 0.f, v = 0.f;
#pragma unroll
  for (int j = 0; j < 8; ++j) {
    u += bf2f((unsigned short)a1[j]);
    v += ln_beta[k + j] * lin_w[(long)n * 2048 + k + j];
  }
#pragma unroll
  for (int off = 1; off < 64; off <<= 1) {
    u += __shfl_xor(u, off);
    v += __shfl_xor(v, off);
  }
  if (lane == 0) { redu[wave] = u; redv[wave] = v; }
  __syncthreads();
  if (t == 0) {
    uV[n] = redu[0] + redu[1] + redu[2] + redu[3];
    vV[n] = redv[0] + redv[1] + redv[2] + redv[3] + lin_b[n];
  }
}

// --------------------------------------------------------------------------
extern "C" void kernel_launch(void* const* d_in, const int* in_sizes, int n_in,
                              void* d_out, int out_size, void* d_ws, size_t ws_size,
                              hipStream_t stream) {
  const float* graph    = (const float*)d_in[0];
  const float* temporal = (const float*)d_in[1];
  const float* gp_w  = (const float*)d_in[2];
  const float* gp_b  = (const float*)d_in[3];
  const float* tp_w  = (const float*)d_in[4];
  const float* tp_b  = (const float*)d_in[5];
  const float* in1_w = (const float*)d_in[6];
  const float* in1_b = (const float*)d_in[7];
  const float* out1_w = (const float*)d_in[8];
  const float* out1_b = (const float*)d_in[9];
  const float* in2_w = (const float*)d_in[10];
  const float* in2_b = (const float*)d_in[11];
  const float* out2_w = (const float*)d_in[12];
  const float* out2_b = (const float*)d_in[13];
  const float* gate_w = (const float*)d_in[14];
  const float* gate_b = (const float*)d_in[15];
  const float* ln_g  = (const float*)d_in[16];
  const float* ln_b  = (const float*)d_in[17];
  const float* lin_w = (const float*)d_in[18];
  const float* lin_b = (const float*)d_in[19];

  const int Bm = 16384, F = 2048, GD = 1024;
  const long BF = (long)Bm * F, FF = (long)F * F, FG = (long)F * GD;

  // ---- ws layout (~164 MB) ----
  unsigned short* TG   = (unsigned short*)d_ws;  // [16384][2048]=[t|g]; later preLN
  unsigned short* PL   = TG;                     // preLN overwrites TG (dead)
  unsigned short* Gbuf = TG + BF;                // g
  unsigned short* wLIN = Gbuf + BF;              // gamma-folded lin_w
  unsigned short* wGP  = wLIN + FF;              // [2048][1024]
  unsigned short* Wcg  = wGP + FG;               // [4096][2048] = [Wcross; Wgate]
  unsigned short* Wcross = Wcg;
  unsigned short* Wgate  = Wcg + FF;
  float* bc2V   = (float*)(Wcg + 2 * FF);        // [4096] = [bcV | bgateV]
  float* uV     = bc2V + 2 * F;
  float* vV     = uV + F;
  float2* stats = (float2*)(vV + F);             // 16384 float2

  // ---- d_out scratch (compose transients; ALL dead before CL GEMM) ----
  unsigned short* DO      = (unsigned short*)d_out;
  unsigned short* wv1T    = DO;            // [2048][2048]
  unsigned short* wv2T    = wv1T + FF;
  unsigned short* tpT     = wv2T + FF;     // [1024][2048]
  unsigned short* gpT     = tpT + FG;
  unsigned short* Wc1     = gpT + FG;      // [2048][2048]
  unsigned short* Wc2     = Wc1 + FF;
  unsigned short* wO1b    = Wc2 + FF;
  unsigned short* wO2b    = wO1b + FF;
  unsigned short* wGATEb  = wO2b + FF;     // [2048][4096]
  unsigned short* WcrossT = wGATEb + 2 * FF;  // [2048][2048]
  unsigned short* CL      = DO;            // [16384][4096] — overwrites all above

  auto conv = [&](const float* src, unsigned short* dst, long n) {
    conv_kernel<<<dim3((unsigned)(n / 8 / 256)), 256, 0, stream>>>(src, dst, (int)n);
  };
  // inputs -> TG = [temporal | graph]
  convcat_kernel<<<dim3((unsigned)(Bm * GD / 8 / 256)), 256, 0, stream>>>(
      temporal, TG, 0, Bm * GD);
  convcat_kernel<<<dim3((unsigned)(Bm * GD / 8 / 256)), 256, 0, stream>>>(
      graph, TG, GD, Bm * GD);
  conv(gp_w, wGP, FG);
  conv(out1_w, wO1b, FF);
  conv(out2_w, wO2b, FF);
  conv(gate_w, wGATEb, 2 * FF);
  convs_kernel<<<dim3((unsigned)(FF / 8 / 256)), 256, 0, stream>>>(lin_w, ln_g, wLIN, (int)FF);
  tconv_kernel<<<dim3(F / 32, F / 32), dim3(32, 8), 0, stream>>>(in1_w + 2 * FF, F, F, wv1T);
  tconv_kernel<<<dim3(F / 32, F / 32), dim3(32, 8), 0, stream>>>(in2_w + 2 * FF, F, F, wv2T);
  tconv_kernel<<<dim3(GD / 32, F / 32), dim3(32, 8), 0, stream>>>(tp_w, F, GD, tpT);
  tconv_kernel<<<dim3(GD / 32, F / 32), dim3(32, 8), 0, stream>>>(gp_w, F, GD, gpT);

  // C1 (pair): Wc1 = wO1@wv1, Wc2 = wO2@wv2   [2048x2048] K=2048
  compose_kernel<CE_PLAIN><<<dim3(512), dim3(256), 0, stream>>>(
      wO1b, F, wv1T, F, Wc1, F, nullptr, 0, F, 16,
      256, wO2b - wO1b, wv2T - wv1T, Wc2 - Wc1);
  // C2 (pair): Wcross = [Wc1@tp_w | Wc2@gp_w] (ws) + transposed copy (d_out)
  compose_kernel<CE_WT><<<dim3(256), dim3(256), 0, stream>>>(
      Wc1, F, tpT, F, Wcross, F, WcrossT, (long)1024 * 2048, F, 16,
      128, Wc2 - Wc1, gpT - tpT, 1024);
  biascompP_kernel<<<dim3(F), dim3(256), 0, stream>>>(
      wO1b, wO2b, Wc1, Wc2, in1_b + 2 * F, in2_b + 2 * F, tp_b, gp_b,
      out1_b, out2_b, bc2V);
  // C3a: Wgate = gw_c @ Wcross  (A = gw_c, W = WcrossT)
  compose_kernel<CE_PLAIN><<<dim3(256), dim3(256), 0, stream>>>(
      wGATEb + F, 2 * F, WcrossT, F, Wgate, F, nullptr, 0, F, 16,
      1 << 30, 0, 0, 0);
  // C3b: Wgate[:,1024:] += gw_g @ gp_w  (A = gw_g, W = gpT)
  compose_kernel<CE_ACC><<<dim3(128), dim3(256), 0, stream>>>(
      wGATEb, 2 * F, gpT, F, Wgate + GD, F, nullptr, 0, F, 16,
      1 << 30, 0, 0, 0);
  bgateP_kernel<<<dim3(F), dim3(256), 0, stream>>>(gate_w, gate_b, gp_b, bc2V,
                                                   bc2V + F);
  uvP_kernel<<<dim3(F), dim3(256), 0, stream>>>(wLIN, lin_w, ln_b, lin_b, uV, vV);

  dim3 blk(512);
  // g = graph @ gp_w^T + gp_b          (K=1024) -> Gbuf
  gemm8p_kernel<EPI_BIAS, 1><<<dim3(512), blk, 0, stream>>>(
      TG + GD, F, wGP, GD, GD, F, 0,
      gp_b, nullptr, nullptr, Gbuf);
  // CL = [cross | logits] = TG @ Wcg^T + bc2V   (K=2048, N=4096) -> d_out
  gemm8p_kernel<EPI_BIAS, 1><<<dim3(1024), blk, 0, stream>>>(
      TG, F, Wcg, F, F, 2 * F, 0,
      bc2V, nullptr, nullptr, CL);
  // fuse gate + residual + LN stats -> PL (=TG region), stats
  fusestats_kernel<<<dim3(Bm), dim3(256), 0, stream>>>(CL, Gbuf, PL, stats);
  // out = rstd*(preLN @ wLIN^T) - rstd*mu*u + v   (K=2048, fp32) -> d_out
  gemm8p_kernel<EPI_LNF32, 1><<<dim3(512), blk, 0, stream>>>(
      PL, F, wLIN, F, F, F, 0,
      uV, vV, stats, (void*)d_out);
}